// Round 7
// baseline (442.909 us; speedup 1.0000x reference)
//
#include <hip/hip_runtime.h>
#include <hip/hip_bf16.h>
#include <cmath>

typedef unsigned short u16;
typedef __attribute__((ext_vector_type(4))) float f32x4;
typedef __attribute__((ext_vector_type(8))) short bf16x8;

// ---------------- problem constants ----------------
#define PVOL   8000
#define CIN    144
#define COUT   72
#define MCH    8

// ---------------- consts (fp32) float-offset layout ----------------
#define OFF_BASIS 10910
#define CONST_BYTES 1110016    // 277504 floats reserved

// XB: [b2][xi26][half2][yi26][zi26][c96] bf16 (zero-padded borders + ch pad)
#define XB_SLICE  64896        // ushorts per (b,xi,half) = 26*26*96
#define XB_BYTES  13498368
// KB: [tap343][half2][ks3][co80][kk32] bf16
#define KB_ELEMS  5268480
#define KB_BYTES  10536960

#define OFF_XB_BYTES   CONST_BYTES
#define OFF_KB_BYTES   (OFF_XB_BYTES + XB_BYTES)
#define OFF_STATS_BYTES (OFF_KB_BYTES + KB_BYTES)

// 19 basis-CG tasks (pair order (lo,li) = 00,01,02,10,11,12,20,21,22)
static __device__ const int T_LO[19]   = {0,0,0,1, 1,1,1, 1,1,1, 2, 2,2,2, 2,2,2,2,2};
static __device__ const int T_LI[19]   = {0,1,2,0, 1,1,1, 2,2,2, 0, 1,1,1, 2,2,2,2,2};
static __device__ const int T_L [19]   = {0,1,2,1, 0,1,2, 1,2,3, 2, 1,2,3, 0,1,2,3,4};
static __device__ const int PAIR_BOFF[9] = {0,1029,4116,9261,12348,40131,86436,91581,137886};
// build_K LDS staging tables
static __device__ const int NL_P[9]   = {1,1,1,1,3,3,1,3,5};
static __device__ const int WSOFF[9]  = {0,384,768,1152,1536,2688,3840,4224,5376};   // 384*nl cumsum (7296 total)
static __device__ const int BSOFF[9]  = {0,3,12,27,36,117,252,267,402};              // PAIR_BOFF/343 (777 total)

// tap tables: (dy<<4)|dz for the r^2<=12 ball, per |dx-3| class
static __device__ const unsigned char TAP_S[9] = {   // dx in {0,6}
  0x22,0x23,0x24, 0x32,0x33,0x34, 0x42,0x43,0x44};
static __device__ const unsigned char TAP_M[25] = {  // dx in {1,5}
  0x11,0x12,0x13,0x14,0x15, 0x21,0x22,0x23,0x24,0x25,
  0x31,0x32,0x33,0x34,0x35, 0x41,0x42,0x43,0x44,0x45,
  0x51,0x52,0x53,0x54,0x55};
static __device__ const unsigned char TAP_B[37] = {  // dx in {2,3,4}
  0x02,0x03,0x04,
  0x11,0x12,0x13,0x14,0x15,
  0x20,0x21,0x22,0x23,0x24,0x25,0x26,
  0x30,0x31,0x32,0x33,0x34,0x35,0x36,
  0x40,0x41,0x42,0x43,0x44,0x45,0x46,
  0x51,0x52,0x53,0x54,0x55,
  0x62,0x63,0x64};

struct WPtrs { const float* p[9]; };

static __device__ inline u16 f2bf(float v){
  __hip_bfloat16 h = __float2bfloat16(v);
  return __builtin_bit_cast(u16, h);
}

// ---------------- device helpers (fp64) ----------------
__device__ inline double d_fact(int n){ double r=1.0; for(int i=2;i<=n;++i) r*=(double)i; return r; }

__device__ double d_su2cg(int j1,int j2,int j3,int m1,int m2,int m3){
  if(m1+m2!=m3) return 0.0;
  if(j3 < abs(j1-j2) || j3 > j1+j2) return 0.0;
  double pref = sqrt((2.0*j3+1.0)*d_fact(j3+j1-j2)*d_fact(j3-j1+j2)*d_fact(j1+j2-j3)/d_fact(j1+j2+j3+1));
  pref *= sqrt(d_fact(j3+m3)*d_fact(j3-m3)*d_fact(j1-m1)*d_fact(j1+m1)*d_fact(j2-m2)*d_fact(j2+m2));
  double s=0.0;
  for(int k=0;k<=j1+j2+j3;++k){
    int d1=j1+j2-j3-k, d2=j1-m1-k, d3=j2+m2-k, d4=j3-j2+m1+k, d5=j3-j1-m2+k;
    if(d1>=0&&d2>=0&&d3>=0&&d4>=0&&d5>=0)
      s += ((k&1)?-1.0:1.0)/(d_fact(k)*d_fact(d1)*d_fact(d2)*d_fact(d3)*d_fact(d4)*d_fact(d5));
  }
  return pref*s;
}

__device__ inline int d_urow(int l, int r, int* col, double* ure, double* uim){
  const double is2 = 0.7071067811865476;
  if(r==l){ col[0]=l; ure[0]=1.0; uim[0]=0.0; return 1; }
  if(r>l){ int m=r-l; double sg=(m&1)?-1.0:1.0;
    col[0]=l+m; ure[0]=sg*is2; uim[0]=0.0;
    col[1]=l-m; ure[1]=is2;    uim[1]=0.0; return 2; }
  int m=l-r;
  col[0]=l-m; ure[0]=0.0; uim[0]=is2;
  col[1]=l+m; ure[1]=0.0; uim[1]=-(((m&1)?-1.0:1.0))*is2;
  return 2;
}

__device__ void d_sph(double gx,double gy,double gz,double Y[25]){
  const double PI_ = 3.14159265358979323846;
  double r = sqrt(gx*gx+gy*gy+gz*gz);
  const double eps=1e-9;
  double ct = (r>eps)? gz/fmax(r,eps) : 1.0;
  double phi = atan2(gy,gx);
  double st2 = 1.0-ct*ct; if(st2<0.0) st2=0.0;
  double st = sqrt(st2);
  double P[5][5];
  P[0][0]=1.0;
  for(int m=1;m<=4;++m){
    double dfac=1.0; for(int k=1;k<2*m;k+=2) dfac*=(double)k;
    double stm=1.0; for(int k=0;k<m;++k) stm*=st;
    P[m][m] = ((m&1)?-1.0:1.0)*dfac*stm;
  }
  for(int m=0;m<4;++m) P[m+1][m] = ct*(2*m+1)*P[m][m];
  for(int m=0;m<=4;++m)
    for(int l=m+2;l<=4;++l)
      P[l][m] = ((2*l-1)*ct*P[l-1][m] - (l+m-1)*P[l-2][m])/(double)(l-m);
  int idx=0;
  for(int l=0;l<=4;++l){
    double arr[9];
    for(int k=0;k<2*l+1;++k) arr[k]=0.0;
    for(int m=0;m<=l;++m){
      double N = sqrt((2.0*l+1.0)/(4.0*PI_)*d_fact(l-m)/d_fact(l+m));
      if(m==0) arr[l] = N*P[l][0];
      else{
        arr[l+m]=sqrt(2.0)*N*P[l][m]*cos(m*phi);
        arr[l-m]=sqrt(2.0)*N*P[l][m]*sin(m*phi);
      }
    }
    if(l>0 && !(r>eps)) for(int k=0;k<2*l+1;++k) arr[k]=0.0;
    for(int k=0;k<2*l+1;++k) Y[idx++]=arr[k];
  }
}

// ---------------- kernel 1: fused CG + Y + RAD + basis (+ TPC) ----------------
__global__ __launch_bounds__(256) void gen_all_kernel(float* __restrict__ consts){
  __shared__ double Cc[225];
  __shared__ float  Tt[225];
  __shared__ float  Ylds[9*343];
  __shared__ float  Rlds[343];
  __shared__ double mre[256], mim[256];
  __shared__ double red[256];
  int tid = threadIdx.x;

  if(blockIdx.x == 57){
    for(int l=0;l<3;++l){
      int n1=3, n2=3, n3=2*l+1, cnt=n1*n2*n3;
      int outOff = (l==0)?0:((l==1)?9:36);
      __syncthreads();
      for(int e=tid;e<cnt;e+=256){
        int m=e/(n2*n3), n=(e/n3)%n2, c=e%n3;
        Cc[e]=d_su2cg(1,1,l, m-1, n-1, c-l);
      }
      __syncthreads();
      double tre=0.0, tim=0.0;
      int e=tid;
      if(e<cnt){
        int a=e/(n1*n2), i=(e/n2)%n1, jj=e%n2;
        int c3[2]; double r3[2], q3[2]; int nc3=d_urow(l,a,c3,r3,q3);
        int c1[2]; double r1[2], q1[2]; int nc1=d_urow(1,i,c1,r1,q1);
        int c2[2]; double r2[2], q2[2]; int nc2=d_urow(1,jj,c2,r2,q2);
        for(int ic=0; ic<nc3; ++ic)
          for(int im=0; im<nc1; ++im)
            for(int in_=0; in_<nc2; ++in_){
              double cc = Cc[(c1[im]*n2 + c2[in_])*n3 + c3[ic]];
              if(cc==0.0) continue;
              double ar=r3[ic], ai=q3[ic];
              double br=r1[im], bi=-q1[im];
              double cr=r2[in_], cim=-q2[in_];
              double abr = ar*br - ai*bi, abi = ar*bi + ai*br;
              double zr = abr*cr - abi*cim, zi = abr*cim + abi*cr;
              tre += zr*cc; tim += zi*cc;
            }
      }
      mre[tid]=fabs(tre); mim[tid]=fabs(tim);
      __syncthreads();
      for(int s=128;s>0;s>>=1){ if(tid<s){ mre[tid]=fmax(mre[tid],mre[tid+s]); mim[tid]=fmax(mim[tid],mim[tid+s]); } __syncthreads(); }
      bool useim = mim[0] > mre[0];
      if(e<cnt) consts[outOff + e] = (float)(useim? tim : tre);
      __syncthreads();
    }
    return;
  }

  int task = blockIdx.x/3, jrad = blockIdx.x%3;
  int lo=T_LO[task], li=T_LI[task], l=T_L[task];
  int j1=li, j2=l, j3=lo;
  int n1=2*j1+1, n2=2*j2+1, n3=2*j3+1, cnt=n1*n2*n3;
  for(int e=tid;e<cnt;e+=256){
    int m=e/(n2*n3), n=(e/n3)%n2, c=e%n3;
    Cc[e]=d_su2cg(j1,j2,j3, m-j1, n-j2, c-j3);
  }
  __syncthreads();
  double tre=0.0, tim=0.0;
  int e=tid;
  if(e<cnt){
    int a=e/(n1*n2), i=(e/n2)%n1, jj=e%n2;
    int c3[2]; double r3[2], q3[2]; int nc3=d_urow(j3,a,c3,r3,q3);
    int c1[2]; double r1[2], q1[2]; int nc1=d_urow(j1,i,c1,r1,q1);
    int c2[2]; double r2[2], q2[2]; int nc2=d_urow(j2,jj,c2,r2,q2);
    for(int ic=0; ic<nc3; ++ic)
      for(int im=0; im<nc1; ++im)
        for(int in_=0; in_<nc2; ++in_){
          double cc = Cc[(c1[im]*n2 + c2[in_])*n3 + c3[ic]];
          if(cc==0.0) continue;
          double ar=r3[ic], ai=q3[ic];
          double br=r1[im], bi=-q1[im];
          double cr=r2[in_], cim=-q2[in_];
          double abr = ar*br - ai*bi, abi = ar*bi + ai*br;
          double zr = abr*cr - abi*cim, zi = abr*cim + abi*cr;
          tre += zr*cc; tim += zi*cc;
        }
  }
  mre[tid]=fabs(tre); mim[tid]=fabs(tim);
  __syncthreads();
  for(int s=128;s>0;s>>=1){ if(tid<s){ mre[tid]=fmax(mre[tid],mre[tid+s]); mim[tid]=fmax(mim[tid],mim[tid+s]); } __syncthreads(); }
  bool useim = mim[0] > mre[0];
  if(e<cnt) Tt[e] = (float)(useim? tim : tre);
  for(int t=tid; t<343; t+=256){
    int ix=t/49, iy=(t/7)%7, iz=t%7;
    double gx=ix-3, gy=iy-3, gz=iz-3;
    double Y25[25]; d_sph(gx,gy,gz,Y25);
    for(int m=0;m<n2;++m) Ylds[m*343+t] = (float)Y25[l*l+m];
    double r = sqrt(gx*gx+gy*gy+gz*gz);
    double d = r - 1.5*jrad;
    Rlds[t] = (r<=3.5)? (float)exp(-0.5*d*d) : 0.0f;
  }
  __syncthreads();
  int A=2*lo+1, I=2*li+1;
  int l_idx = l - abs(lo-li);
  float* out = consts + OFF_BASIS + PAIR_BOFF[lo*3+li] + (size_t)((l_idx*3 + jrad)*A*I)*343;
  int N = A*I*343;
  double ssq = 0.0;
  for(int ee=tid; ee<N; ee+=256){
    int ai = ee/343, t = ee%343;
    double ang = 0.0;
    for(int m=0;m<n2;++m) ang += (double)Tt[ai*n2+m] * (double)Ylds[m*343+t];
    double val = ang * (double)Rlds[t];
    out[ee] = (float)val;
    ssq += val*val;
  }
  red[tid]=ssq; __syncthreads();
  for(int s=128;s>0;s>>=1){ if(tid<s) red[tid]+=red[tid+s]; __syncthreads(); }
  double nrm = sqrt(red[0]);
  float scale = (nrm>1e-12)? (float)(1.0/nrm) : 1.0f;
  for(int ee=tid; ee<N; ee+=256) out[ee] *= scale;
}

// ---------------- kernel 3: build padded bf16 xin (fragment-native layout) ----------------
__global__ __launch_bounds__(256) void build_xin_kernel(const float* __restrict__ x,
    const float* __restrict__ consts, u16* __restrict__ XB){
  int id = blockIdx.x*256 + threadIdx.x;
  if(id >= 2*MCH*PVOL) return;
  int p = id % PVOL; int u = (id/PVOL)%MCH; int b = id/(MCH*PVOL);
  int xi=p/400, rr=p%400, yi=rr/20, zi=rr%20;
  const float* xb = x + (size_t)b*COUT*PVOL + p;
  float s  = xb[(size_t)u*PVOL];
  float vv[3], qq[5];
  for(int i=0;i<3;++i) vv[i] = xb[(size_t)(8+u*3+i)*PVOL];
  for(int i=0;i<5;++i) qq[i] = xb[(size_t)(32+u*5+i)*PVOL];
  const float* T0 = consts + 0;
  const float* T1 = consts + 9;
  const float* T2 = consts + 36;
  float i0=0.f, i1[3]={0,0,0}, i2[5]={0,0,0,0,0};
  for(int i=0;i<3;++i) for(int jj=0;jj<3;++jj){
    float vij = vv[i]*vv[jj];
    i0 += T0[i*3+jj]*vij;
    for(int a=0;a<3;++a) i1[a] += T1[(a*3+i)*3+jj]*vij;
    for(int a=0;a<5;++a) i2[a] += T2[(a*3+i)*3+jj]*vij;
  }
  size_t base_b = ((size_t)b*26 + (xi+3))*2;
  size_t pos = ((size_t)(yi+3))*26 + (zi+3);
  auto wr = [&](int ci, float v){
    int h = ci>=80 ? 1 : 0; int cl = ci - 80*h;
    XB[(base_b + h)*XB_SLICE + pos*96 + cl] = f2bf(v);
  };
  wr(u, s);
  wr(8+u, i0);
  for(int i=0;i<3;++i) wr(16+u*3+i, vv[i]);
  for(int a=0;a<3;++a) wr(40+u*3+a, i1[a]);
  for(int i=0;i<5;++i) wr(64+u*5+i, qq[i]);
  for(int a=0;a<5;++a) wr(104+u*5+a, i2[a]);
}

// ---------------- kernel 4: build K (one block per tap, LDS-staged w+basis) ----------------
__global__ __launch_bounds__(256) void build_K_kernel(WPtrs W,
    const float* __restrict__ consts, u16* __restrict__ KB){
  int tap = blockIdx.x, tid = threadIdx.x;
  __shared__ float ws[7296];
  __shared__ float bs[777];
  for(int p=0;p<9;++p){
    int n = 384*NL_P[p];
    const float* wp = W.p[p];
    for(int e=tid; e<n; e+=256) ws[WSOFF[p]+e] = wp[e];
  }
  for(int f=tid; f<777; f+=256) bs[f] = consts[OFF_BASIS + f*343 + tap];
  __syncthreads();
  for(int o=tid; o<15360; o+=256){
    int kk = o&31;
    int co = (o>>5)%80;
    int ks = (o/2560)%3;
    int half = o/7680;
    int ci_l = ks*32 + kk;
    float acc = 0.f;
    bool valid = (co<72) && (half==0 ? (ci_l<80) : (ci_l<64));
    if(valid){
      int ci = half*80 + ci_l;
      int lo,u,a;
      if(co<8){ lo=0; u=co; a=0; }
      else if(co<32){ lo=1; u=(co-8)/3; a=(co-8)%3; }
      else { lo=2; u=(co-32)/5; a=(co-32)%5; }
      int li,vv,i;
      if(ci<16){ li=0; vv=ci; i=0; }
      else if(ci<64){ li=1; vv=(ci-16)/3; i=(ci-16)%3; }
      else { li=2; vv=(ci-64)/5; i=(ci-64)%5; }
      int p = lo*3+li;
      int nl = NL_P[p];
      int A = 2*lo+1, I = 2*li+1;
      const float* wb = ws + WSOFF[p] + (u*16+vv)*nl*3;
      const float* bb = bs + BSOFF[p];
      for(int lk=0; lk<nl; ++lk)
        for(int j=0;j<3;++j)
          acc = fmaf(wb[lk*3+j], bb[((lk*3+j)*A + a)*I + i], acc);
    }
    KB[(size_t)tap*15360 + o] = f2bf(acc);
  }
}

// ---------------- kernel 5: MFMA implicit-GEMM conv, static 6-slot pipeline ----------------
#define RS 104   // LDS row stride (ushorts)
#define MF(a,b,c) __builtin_amdgcn_mfma_f32_16x16x32_bf16(a,b,c,0,0,0)

struct AF { bf16x8 a0,a1,a2,a3,a4; };
struct BF { bf16x8 b0,b1,b2,b3; };

// A-frag load: desc.x = tap*15360
#define LDA_(BUF, dsc, kss) { \
  const u16* ka_ = KB + (dsc).x + hoff + (kss)*2560 + aoff; \
  BUF.a0 = *(const bf16x8*)(ka_);       \
  BUF.a1 = *(const bf16x8*)(ka_+512);   \
  BUF.a2 = *(const bf16x8*)(ka_+1024);  \
  BUF.a3 = *(const bf16x8*)(ka_+1536);  \
  BUF.a4 = *(const bf16x8*)(ka_+2048);  }
// B-frag load: desc.y = (dy*26+dz)*RS
#define LDB_(BUF, dsc, kss) { \
  const u16* bp_ = Bl + (dsc).y + (kss)*32 + boff; \
  BUF.b0 = *(const bf16x8*)(bp_ + rB0); \
  BUF.b1 = *(const bf16x8*)(bp_ + rB1); \
  BUF.b2 = *(const bf16x8*)(bp_ + rB2); \
  BUF.b3 = *(const bf16x8*)(bp_ + rB3); }

#define DOSLOT(Ab,Bb) { \
  __builtin_amdgcn_s_setprio(1); \
  acc[0][0]=MF(Ab.a0,Bb.b0,acc[0][0]); acc[1][0]=MF(Ab.a1,Bb.b0,acc[1][0]); \
  acc[2][0]=MF(Ab.a2,Bb.b0,acc[2][0]); acc[3][0]=MF(Ab.a3,Bb.b0,acc[3][0]); \
  acc[4][0]=MF(Ab.a4,Bb.b0,acc[4][0]); \
  acc[0][1]=MF(Ab.a0,Bb.b1,acc[0][1]); acc[1][1]=MF(Ab.a1,Bb.b1,acc[1][1]); \
  acc[2][1]=MF(Ab.a2,Bb.b1,acc[2][1]); acc[3][1]=MF(Ab.a3,Bb.b1,acc[3][1]); \
  acc[4][1]=MF(Ab.a4,Bb.b1,acc[4][1]); \
  acc[0][2]=MF(Ab.a0,Bb.b2,acc[0][2]); acc[1][2]=MF(Ab.a1,Bb.b2,acc[1][2]); \
  acc[2][2]=MF(Ab.a2,Bb.b2,acc[2][2]); acc[3][2]=MF(Ab.a3,Bb.b2,acc[3][2]); \
  acc[4][2]=MF(Ab.a4,Bb.b2,acc[4][2]); \
  if(NF4){ \
    acc[0][3]=MF(Ab.a0,Bb.b3,acc[0][3]); acc[1][3]=MF(Ab.a1,Bb.b3,acc[1][3]); \
    acc[2][3]=MF(Ab.a2,Bb.b3,acc[2][3]); acc[3][3]=MF(Ab.a3,Bb.b3,acc[3][3]); \
    acc[4][3]=MF(Ab.a4,Bb.b3,acc[4][3]); } \
  __builtin_amdgcn_s_setprio(0); }

// __launch_bounds__(512, 2): 2 waves/EU min -> 256-VGPR budget. Without it the
// compiler targets 4 waves/EU (128 VGPR) and SPILLS the pipeline (round-6: 250MB
// scratch writes). LDS (140.6KB) caps us at 1 block/CU = 2 waves/EU anyway.
__global__ __launch_bounds__(512, 2) void conv_mfma(const u16* __restrict__ XB,
    const u16* __restrict__ KB, float* __restrict__ y){
  __shared__ __align__(16) u16 Bl[676*RS];   // 140,608 B
  __shared__ int2 tdesc[37];
  int wg = blockIdx.x;
  int swz = (wg & 7)*30 + (wg >> 3);   // XCD-chunked, bijective (240 = 8*30)
  int xo = swz % 20; int g = (swz/20) % 6; int b = swz/120;
  int tid = threadIdx.x;
  int w = tid>>6, l = tid&63, lrow = l&15, lseg = l>>4;
  int nf0 = (w<7)? w*3 : 21;
  bool NF4 = (w==7);
  int aoff = lrow*32 + lseg*8;
  int boff = lseg*8;
  f32x4 acc[5][4];
  #pragma unroll
  for(int mf=0;mf<5;++mf)
    #pragma unroll
    for(int f=0;f<4;++f) acc[mf][f] = (f32x4){0.f,0.f,0.f,0.f};
  int rB0, rB1, rB2, rB3;
  { int n;
    n=(nf0+0)*16+lrow; rB0=((n/20)*26+(n%20))*RS;
    n=(nf0+1)*16+lrow; rB1=((n/20)*26+(n%20))*RS;
    n=(nf0+2)*16+lrow; rB2=((n/20)*26+(n%20))*RS;
    n=(nf0+3)*16+lrow; rB3=((n/20)*26+(n%20))*RS; }

  int ndx = (g==0)? 2 : 1;
  for(int id=0; id<ndx; ++id){
    int dx = (g==0)? id*6 : g;
    const unsigned char* tl; int nt;
    if(dx==0 || dx==6){ tl = TAP_S; nt = 9; }
    else if(dx==1 || dx==5){ tl = TAP_M; nt = 25; }
    else { tl = TAP_B; nt = 37; }
    __syncthreads();                 // prior pipeline done before desc rewrite
    if(tid < nt){
      int code = tl[tid];
      int dy = code>>4, dz = code&15;
      tdesc[tid] = make_int2((dx*49+dy*7+dz)*15360, (dy*26+dz)*RS);
    }
    for(int half=0; half<2; ++half){
      __syncthreads();
      const u16* src = XB + ((size_t)(b*26 + xo + dx)*2 + half)*XB_SLICE;
      for(int c=tid; c<8112; c+=512){
        ulonglong2 v = ((const ulonglong2*)src)[c];
        int row = c/12, wi = c - row*12;
        *(ulonglong2*)(Bl + row*RS + wi*8) = v;
      }
      __syncthreads();
      int hoff = half*7680;
      AF X, Y, Z; BF P, Q;
      int2 dd0 = tdesc[0];
      LDA_(X, dd0, 0);
      LDA_(Y, dd0, 1);
      LDB_(P, dd0, 0);
      if(half==0){
        // KS = 3 : 2-tap (6-slot) unrolled body, 1-tap epilogue (nt odd)
        int t = 0;
        for(; t+2 < nt; t += 2){
          int2 e0 = tdesc[t], e1 = tdesc[t+1], e2 = tdesc[t+2];
          LDB_(Q, e0, 1);  LDA_(Z, e0, 2);  DOSLOT(X, P);
          LDB_(P, e0, 2);  LDA_(X, e1, 0);  DOSLOT(Y, Q);
          LDB_(Q, e1, 0);  LDA_(Y, e1, 1);  DOSLOT(Z, P);
          LDB_(P, e1, 1);  LDA_(Z, e1, 2);  DOSLOT(X, Q);
          LDB_(Q, e1, 2);  LDA_(X, e2, 0);  DOSLOT(Y, P);
          LDB_(P, e2, 0);  LDA_(Y, e2, 1);  DOSLOT(Z, Q);
        }
        // epilogue tap T = nt-1: X,Y hold (T,0),(T,1); P holds (T,0)
        int2 eT = tdesc[nt-1];
        LDB_(Q, eT, 1);  LDA_(Z, eT, 2);  DOSLOT(X, P);
        LDB_(P, eT, 2);                   DOSLOT(Y, Q);
                                          DOSLOT(Z, P);
      } else {
        // KS = 2 : 3-tap (6-slot) unrolled body, serial tail
        int t = 0;
        for(; t+3 < nt; t += 3){
          int2 e0 = tdesc[t], e1 = tdesc[t+1], e2 = tdesc[t+2], e3 = tdesc[t+3];
          LDB_(Q, e0, 1);  LDA_(Z, e1, 0);  DOSLOT(X, P);
          LDB_(P, e1, 0);  LDA_(X, e1, 1);  DOSLOT(Y, Q);
          LDB_(Q, e1, 1);  LDA_(Y, e2, 0);  DOSLOT(Z, P);
          LDB_(P, e2, 0);  LDA_(Z, e2, 1);  DOSLOT(X, Q);
          LDB_(Q, e2, 1);  LDA_(X, e3, 0);  DOSLOT(Y, P);
          LDB_(P, e3, 0);  LDA_(Y, e3, 1);  DOSLOT(Z, Q);
        }
        // serial tail: taps t..nt-1 (1 or 3 taps), depth-0
        for(; t < nt; ++t){
          int2 eT = tdesc[t];
          LDA_(X, eT, 0);  LDB_(P, eT, 0);  DOSLOT(X, P);
          LDA_(X, eT, 1);  LDB_(P, eT, 1);  DOSLOT(X, P);
        }
      }
    }
  }
  // epilogue: atomic combine across the 6 dx-groups. C/D: col=lane&15 (n), row=(lane>>4)*4+r (co)
  int NFc = NF4 ? 4 : 3;
  #pragma unroll
  for(int f=0; f<4; ++f){
    if(f < NFc){
      int n = (nf0+f)*16 + lrow;
      #pragma unroll
      for(int mf=0; mf<5; ++mf){
        #pragma unroll
        for(int r=0; r<4; ++r){
          int co = mf*16 + lseg*4 + r;
          if(co < 72)
            atomicAdd(&y[((size_t)(b*COUT+co)*20 + xo)*400 + n], acc[mf][f][r]);
        }
      }
    }
  }
}

// ---------------- kernel 6: bn partial sums (grid 24 x 16, atomic combine) ----------------
__global__ __launch_bounds__(256) void bn_partial_kernel(const float* __restrict__ y,
    float* __restrict__ stats){
  int g = blockIdx.x, chunk = blockIdx.y, tid = threadIdx.x;
  int ch0, nc;
  if(g<8){ ch0=g; nc=1; }
  else if(g<16){ ch0=8+(g-8)*3; nc=3; }
  else { ch0=32+(g-16)*5; nc=5; }
  float s=0.f;
  int lo = chunk*1000, hi = lo+1000;
  for(int idx=lo+tid; idx<hi; idx+=256){
    int b = idx/PVOL, p = idx%PVOL;
    const float* yb = y + ((size_t)b*COUT + ch0)*PVOL + p;
    for(int c=0;c<nc;++c){ float v = yb[(size_t)c*PVOL]; s += v*v; }
  }
  __shared__ float red[256];
  red[tid]=s; __syncthreads();
  for(int st=128; st>0; st>>=1){ if(tid<st) red[tid]+=red[tid+st]; __syncthreads(); }
  if(tid==0) atomicAdd(&stats[g], red[0]);
}

// ---------------- kernel 7: apply scale/bias/relu ----------------
__global__ __launch_bounds__(256) void apply_kernel(float* __restrict__ y,
    const float* __restrict__ stats, const float* __restrict__ gamma,
    const float* __restrict__ bias){
  int id = blockIdx.x*256 + threadIdx.x;
  if(id >= 2*COUT*PVOL) return;
  int c = (id/PVOL)%COUT;
  int g = (c<8)? c : ((c<32)? 8+(c-8)/3 : 16+(c-32)/5);
  float scale = gamma[g]*rsqrtf(stats[g]*(1.f/16000.f) + 1e-5f);
  float val = y[id]*scale;
  if(c<8) val = fmaxf(val + bias[c], 0.f);
  y[id] = val;
}

// ---------------- launch ----------------
extern "C" void kernel_launch(void* const* d_in, const int* in_sizes, int n_in,
                              void* d_out, int out_size, void* d_ws, size_t ws_size,
                              hipStream_t stream){
  const float* x = (const float*)d_in[0];
  WPtrs W;
  for(int k=0;k<9;++k) W.p[k] = (const float*)d_in[1+k];
  const float* gamma = (const float*)d_in[10];
  const float* bias  = (const float*)d_in[11];
  char* base = (char*)d_ws;
  float* consts = (float*)base;
  u16* XB = (u16*)(base + OFF_XB_BYTES);
  u16* KB = (u16*)(base + OFF_KB_BYTES);
  float* stats = (float*)(base + OFF_STATS_BYTES);
  float* y = (float*)d_out;

  hipMemsetAsync(XB, 0, XB_BYTES, stream);
  hipMemsetAsync(y, 0, (size_t)2*COUT*PVOL*sizeof(float), stream);
  hipMemsetAsync(stats, 0, 24*sizeof(float), stream);
  gen_all_kernel<<<58,256,0,stream>>>(consts);
  build_xin_kernel<<<(2*MCH*PVOL+255)/256,256,0,stream>>>(x, consts, XB);
  build_K_kernel<<<343,256,0,stream>>>(W, consts, KB);
  conv_mfma<<<240,512,0,stream>>>(XB, KB, y);
  bn_partial_kernel<<<dim3(24,16),256,0,stream>>>(y, stats);
  apply_kernel<<<(2*COUT*PVOL+255)/256,256,0,stream>>>(y, stats, gamma, bias);
}

// Round 8
// 442.216 us; speedup vs baseline: 1.0016x; 1.0016x over previous
//
#include <hip/hip_runtime.h>
#include <hip/hip_bf16.h>
#include <cmath>

typedef unsigned short u16;
typedef __attribute__((ext_vector_type(4))) float f32x4;
typedef __attribute__((ext_vector_type(8))) short bf16x8;

// ---------------- problem constants ----------------
#define PVOL   8000
#define CIN    144
#define COUT   72
#define MCH    8

// ---------------- consts (fp32) float-offset layout ----------------
#define OFF_BASIS 10910
#define CONST_BYTES 1110016    // 277504 floats reserved

// XB: [b2][xi26][half2][yi26][zi26][c96] bf16 (zero-padded borders + ch pad)
#define XB_SLICE  64896        // ushorts per (b,xi,half) = 26*26*96
#define XB_BYTES  13498368
// KB: [tap343][half2][ks3][co80][kk32] bf16
#define KB_ELEMS  5268480
#define KB_BYTES  10536960

#define OFF_XB_BYTES   CONST_BYTES
#define OFF_KB_BYTES   (OFF_XB_BYTES + XB_BYTES)
#define OFF_STATS_BYTES (OFF_KB_BYTES + KB_BYTES)

// 19 basis-CG tasks (pair order (lo,li) = 00,01,02,10,11,12,20,21,22)
static __device__ const int T_LO[19]   = {0,0,0,1, 1,1,1, 1,1,1, 2, 2,2,2, 2,2,2,2,2};
static __device__ const int T_LI[19]   = {0,1,2,0, 1,1,1, 2,2,2, 0, 1,1,1, 2,2,2,2,2};
static __device__ const int T_L [19]   = {0,1,2,1, 0,1,2, 1,2,3, 2, 1,2,3, 0,1,2,3,4};
static __device__ const int PAIR_BOFF[9] = {0,1029,4116,9261,12348,40131,86436,91581,137886};
// build_K LDS staging tables
static __device__ const int NL_P[9]   = {1,1,1,1,3,3,1,3,5};
static __device__ const int WSOFF[9]  = {0,384,768,1152,1536,2688,3840,4224,5376};   // 384*nl cumsum (7296 total)
static __device__ const int BSOFF[9]  = {0,3,12,27,36,117,252,267,402};              // PAIR_BOFF/343 (777 total)

// tap tables: (dy<<4)|dz for the r^2<=12 ball, per |dx-3| class
static __device__ const unsigned char TAP_S[9] = {   // dx in {0,6}
  0x22,0x23,0x24, 0x32,0x33,0x34, 0x42,0x43,0x44};
static __device__ const unsigned char TAP_M[25] = {  // dx in {1,5}
  0x11,0x12,0x13,0x14,0x15, 0x21,0x22,0x23,0x24,0x25,
  0x31,0x32,0x33,0x34,0x35, 0x41,0x42,0x43,0x44,0x45,
  0x51,0x52,0x53,0x54,0x55};
static __device__ const unsigned char TAP_B[37] = {  // dx in {2,3,4}
  0x02,0x03,0x04,
  0x11,0x12,0x13,0x14,0x15,
  0x20,0x21,0x22,0x23,0x24,0x25,0x26,
  0x30,0x31,0x32,0x33,0x34,0x35,0x36,
  0x40,0x41,0x42,0x43,0x44,0x45,0x46,
  0x51,0x52,0x53,0x54,0x55,
  0x62,0x63,0x64};

struct WPtrs { const float* p[9]; };

static __device__ inline u16 f2bf(float v){
  __hip_bfloat16 h = __float2bfloat16(v);
  return __builtin_bit_cast(u16, h);
}

// ---------------- device helpers (fp64) ----------------
__device__ inline double d_fact(int n){ double r=1.0; for(int i=2;i<=n;++i) r*=(double)i; return r; }

__device__ double d_su2cg(int j1,int j2,int j3,int m1,int m2,int m3){
  if(m1+m2!=m3) return 0.0;
  if(j3 < abs(j1-j2) || j3 > j1+j2) return 0.0;
  double pref = sqrt((2.0*j3+1.0)*d_fact(j3+j1-j2)*d_fact(j3-j1+j2)*d_fact(j1+j2-j3)/d_fact(j1+j2+j3+1));
  pref *= sqrt(d_fact(j3+m3)*d_fact(j3-m3)*d_fact(j1-m1)*d_fact(j1+m1)*d_fact(j2-m2)*d_fact(j2+m2));
  double s=0.0;
  for(int k=0;k<=j1+j2+j3;++k){
    int d1=j1+j2-j3-k, d2=j1-m1-k, d3=j2+m2-k, d4=j3-j2+m1+k, d5=j3-j1-m2+k;
    if(d1>=0&&d2>=0&&d3>=0&&d4>=0&&d5>=0)
      s += ((k&1)?-1.0:1.0)/(d_fact(k)*d_fact(d1)*d_fact(d2)*d_fact(d3)*d_fact(d4)*d_fact(d5));
  }
  return pref*s;
}

__device__ inline int d_urow(int l, int r, int* col, double* ure, double* uim){
  const double is2 = 0.7071067811865476;
  if(r==l){ col[0]=l; ure[0]=1.0; uim[0]=0.0; return 1; }
  if(r>l){ int m=r-l; double sg=(m&1)?-1.0:1.0;
    col[0]=l+m; ure[0]=sg*is2; uim[0]=0.0;
    col[1]=l-m; ure[1]=is2;    uim[1]=0.0; return 2; }
  int m=l-r;
  col[0]=l-m; ure[0]=0.0; uim[0]=is2;
  col[1]=l+m; ure[1]=0.0; uim[1]=-(((m&1)?-1.0:1.0))*is2;
  return 2;
}

__device__ void d_sph(double gx,double gy,double gz,double Y[25]){
  const double PI_ = 3.14159265358979323846;
  double r = sqrt(gx*gx+gy*gy+gz*gz);
  const double eps=1e-9;
  double ct = (r>eps)? gz/fmax(r,eps) : 1.0;
  double phi = atan2(gy,gx);
  double st2 = 1.0-ct*ct; if(st2<0.0) st2=0.0;
  double st = sqrt(st2);
  double P[5][5];
  P[0][0]=1.0;
  for(int m=1;m<=4;++m){
    double dfac=1.0; for(int k=1;k<2*m;k+=2) dfac*=(double)k;
    double stm=1.0; for(int k=0;k<m;++k) stm*=st;
    P[m][m] = ((m&1)?-1.0:1.0)*dfac*stm;
  }
  for(int m=0;m<4;++m) P[m+1][m] = ct*(2*m+1)*P[m][m];
  for(int m=0;m<=4;++m)
    for(int l=m+2;l<=4;++l)
      P[l][m] = ((2*l-1)*ct*P[l-1][m] - (l+m-1)*P[l-2][m])/(double)(l-m);
  int idx=0;
  for(int l=0;l<=4;++l){
    double arr[9];
    for(int k=0;k<2*l+1;++k) arr[k]=0.0;
    for(int m=0;m<=l;++m){
      double N = sqrt((2.0*l+1.0)/(4.0*PI_)*d_fact(l-m)/d_fact(l+m));
      if(m==0) arr[l] = N*P[l][0];
      else{
        arr[l+m]=sqrt(2.0)*N*P[l][m]*cos(m*phi);
        arr[l-m]=sqrt(2.0)*N*P[l][m]*sin(m*phi);
      }
    }
    if(l>0 && !(r>eps)) for(int k=0;k<2*l+1;++k) arr[k]=0.0;
    for(int k=0;k<2*l+1;++k) Y[idx++]=arr[k];
  }
}

// ---------------- kernel 1: fused CG + Y + RAD + basis (+ TPC) ----------------
__global__ __launch_bounds__(256) void gen_all_kernel(float* __restrict__ consts){
  __shared__ double Cc[225];
  __shared__ float  Tt[225];
  __shared__ float  Ylds[9*343];
  __shared__ float  Rlds[343];
  __shared__ double mre[256], mim[256];
  __shared__ double red[256];
  int tid = threadIdx.x;

  if(blockIdx.x == 57){
    for(int l=0;l<3;++l){
      int n1=3, n2=3, n3=2*l+1, cnt=n1*n2*n3;
      int outOff = (l==0)?0:((l==1)?9:36);
      __syncthreads();
      for(int e=tid;e<cnt;e+=256){
        int m=e/(n2*n3), n=(e/n3)%n2, c=e%n3;
        Cc[e]=d_su2cg(1,1,l, m-1, n-1, c-l);
      }
      __syncthreads();
      double tre=0.0, tim=0.0;
      int e=tid;
      if(e<cnt){
        int a=e/(n1*n2), i=(e/n2)%n1, jj=e%n2;
        int c3[2]; double r3[2], q3[2]; int nc3=d_urow(l,a,c3,r3,q3);
        int c1[2]; double r1[2], q1[2]; int nc1=d_urow(1,i,c1,r1,q1);
        int c2[2]; double r2[2], q2[2]; int nc2=d_urow(1,jj,c2,r2,q2);
        for(int ic=0; ic<nc3; ++ic)
          for(int im=0; im<nc1; ++im)
            for(int in_=0; in_<nc2; ++in_){
              double cc = Cc[(c1[im]*n2 + c2[in_])*n3 + c3[ic]];
              if(cc==0.0) continue;
              double ar=r3[ic], ai=q3[ic];
              double br=r1[im], bi=-q1[im];
              double cr=r2[in_], cim=-q2[in_];
              double abr = ar*br - ai*bi, abi = ar*bi + ai*br;
              double zr = abr*cr - abi*cim, zi = abr*cim + abi*cr;
              tre += zr*cc; tim += zi*cc;
            }
      }
      mre[tid]=fabs(tre); mim[tid]=fabs(tim);
      __syncthreads();
      for(int s=128;s>0;s>>=1){ if(tid<s){ mre[tid]=fmax(mre[tid],mre[tid+s]); mim[tid]=fmax(mim[tid],mim[tid+s]); } __syncthreads(); }
      bool useim = mim[0] > mre[0];
      if(e<cnt) consts[outOff + e] = (float)(useim? tim : tre);
      __syncthreads();
    }
    return;
  }

  int task = blockIdx.x/3, jrad = blockIdx.x%3;
  int lo=T_LO[task], li=T_LI[task], l=T_L[task];
  int j1=li, j2=l, j3=lo;
  int n1=2*j1+1, n2=2*j2+1, n3=2*j3+1, cnt=n1*n2*n3;
  for(int e=tid;e<cnt;e+=256){
    int m=e/(n2*n3), n=(e/n3)%n2, c=e%n3;
    Cc[e]=d_su2cg(j1,j2,j3, m-j1, n-j2, c-j3);
  }
  __syncthreads();
  double tre=0.0, tim=0.0;
  int e=tid;
  if(e<cnt){
    int a=e/(n1*n2), i=(e/n2)%n1, jj=e%n2;
    int c3[2]; double r3[2], q3[2]; int nc3=d_urow(j3,a,c3,r3,q3);
    int c1[2]; double r1[2], q1[2]; int nc1=d_urow(j1,i,c1,r1,q1);
    int c2[2]; double r2[2], q2[2]; int nc2=d_urow(j2,jj,c2,r2,q2);
    for(int ic=0; ic<nc3; ++ic)
      for(int im=0; im<nc1; ++im)
        for(int in_=0; in_<nc2; ++in_){
          double cc = Cc[(c1[im]*n2 + c2[in_])*n3 + c3[ic]];
          if(cc==0.0) continue;
          double ar=r3[ic], ai=q3[ic];
          double br=r1[im], bi=-q1[im];
          double cr=r2[in_], cim=-q2[in_];
          double abr = ar*br - ai*bi, abi = ar*bi + ai*br;
          double zr = abr*cr - abi*cim, zi = abr*cim + abi*cr;
          tre += zr*cc; tim += zi*cc;
        }
  }
  mre[tid]=fabs(tre); mim[tid]=fabs(tim);
  __syncthreads();
  for(int s=128;s>0;s>>=1){ if(tid<s){ mre[tid]=fmax(mre[tid],mre[tid+s]); mim[tid]=fmax(mim[tid],mim[tid+s]); } __syncthreads(); }
  bool useim = mim[0] > mre[0];
  if(e<cnt) Tt[e] = (float)(useim? tim : tre);
  for(int t=tid; t<343; t+=256){
    int ix=t/49, iy=(t/7)%7, iz=t%7;
    double gx=ix-3, gy=iy-3, gz=iz-3;
    double Y25[25]; d_sph(gx,gy,gz,Y25);
    for(int m=0;m<n2;++m) Ylds[m*343+t] = (float)Y25[l*l+m];
    double r = sqrt(gx*gx+gy*gy+gz*gz);
    double d = r - 1.5*jrad;
    Rlds[t] = (r<=3.5)? (float)exp(-0.5*d*d) : 0.0f;
  }
  __syncthreads();
  int A=2*lo+1, I=2*li+1;
  int l_idx = l - abs(lo-li);
  float* out = consts + OFF_BASIS + PAIR_BOFF[lo*3+li] + (size_t)((l_idx*3 + jrad)*A*I)*343;
  int N = A*I*343;
  double ssq = 0.0;
  for(int ee=tid; ee<N; ee+=256){
    int ai = ee/343, t = ee%343;
    double ang = 0.0;
    for(int m=0;m<n2;++m) ang += (double)Tt[ai*n2+m] * (double)Ylds[m*343+t];
    double val = ang * (double)Rlds[t];
    out[ee] = (float)val;
    ssq += val*val;
  }
  red[tid]=ssq; __syncthreads();
  for(int s=128;s>0;s>>=1){ if(tid<s) red[tid]+=red[tid+s]; __syncthreads(); }
  double nrm = sqrt(red[0]);
  float scale = (nrm>1e-12)? (float)(1.0/nrm) : 1.0f;
  for(int ee=tid; ee<N; ee+=256) out[ee] *= scale;
}

// ---------------- kernel 3: build padded bf16 xin (fragment-native layout) ----------------
__global__ __launch_bounds__(256) void build_xin_kernel(const float* __restrict__ x,
    const float* __restrict__ consts, u16* __restrict__ XB){
  int id = blockIdx.x*256 + threadIdx.x;
  if(id >= 2*MCH*PVOL) return;
  int p = id % PVOL; int u = (id/PVOL)%MCH; int b = id/(MCH*PVOL);
  int xi=p/400, rr=p%400, yi=rr/20, zi=rr%20;
  const float* xb = x + (size_t)b*COUT*PVOL + p;
  float s  = xb[(size_t)u*PVOL];
  float vv[3], qq[5];
  for(int i=0;i<3;++i) vv[i] = xb[(size_t)(8+u*3+i)*PVOL];
  for(int i=0;i<5;++i) qq[i] = xb[(size_t)(32+u*5+i)*PVOL];
  const float* T0 = consts + 0;
  const float* T1 = consts + 9;
  const float* T2 = consts + 36;
  float i0=0.f, i1[3]={0,0,0}, i2[5]={0,0,0,0,0};
  for(int i=0;i<3;++i) for(int jj=0;jj<3;++jj){
    float vij = vv[i]*vv[jj];
    i0 += T0[i*3+jj]*vij;
    for(int a=0;a<3;++a) i1[a] += T1[(a*3+i)*3+jj]*vij;
    for(int a=0;a<5;++a) i2[a] += T2[(a*3+i)*3+jj]*vij;
  }
  size_t base_b = ((size_t)b*26 + (xi+3))*2;
  size_t pos = ((size_t)(yi+3))*26 + (zi+3);
  auto wr = [&](int ci, float v){
    int h = ci>=80 ? 1 : 0; int cl = ci - 80*h;
    XB[(base_b + h)*XB_SLICE + pos*96 + cl] = f2bf(v);
  };
  wr(u, s);
  wr(8+u, i0);
  for(int i=0;i<3;++i) wr(16+u*3+i, vv[i]);
  for(int a=0;a<3;++a) wr(40+u*3+a, i1[a]);
  for(int i=0;i<5;++i) wr(64+u*5+i, qq[i]);
  for(int a=0;a<5;++a) wr(104+u*5+a, i2[a]);
}

// ---------------- kernel 4: build K (one block per tap, LDS-staged w+basis) ----------------
__global__ __launch_bounds__(256) void build_K_kernel(WPtrs W,
    const float* __restrict__ consts, u16* __restrict__ KB){
  int tap = blockIdx.x, tid = threadIdx.x;
  __shared__ float ws[7296];
  __shared__ float bs[777];
  for(int p=0;p<9;++p){
    int n = 384*NL_P[p];
    const float* wp = W.p[p];
    for(int e=tid; e<n; e+=256) ws[WSOFF[p]+e] = wp[e];
  }
  for(int f=tid; f<777; f+=256) bs[f] = consts[OFF_BASIS + f*343 + tap];
  __syncthreads();
  for(int o=tid; o<15360; o+=256){
    int kk = o&31;
    int co = (o>>5)%80;
    int ks = (o/2560)%3;
    int half = o/7680;
    int ci_l = ks*32 + kk;
    float acc = 0.f;
    bool valid = (co<72) && (half==0 ? (ci_l<80) : (ci_l<64));
    if(valid){
      int ci = half*80 + ci_l;
      int lo,u,a;
      if(co<8){ lo=0; u=co; a=0; }
      else if(co<32){ lo=1; u=(co-8)/3; a=(co-8)%3; }
      else { lo=2; u=(co-32)/5; a=(co-32)%5; }
      int li,vv,i;
      if(ci<16){ li=0; vv=ci; i=0; }
      else if(ci<64){ li=1; vv=(ci-16)/3; i=(ci-16)%3; }
      else { li=2; vv=(ci-64)/5; i=(ci-64)%5; }
      int p = lo*3+li;
      int nl = NL_P[p];
      int A = 2*lo+1, I = 2*li+1;
      const float* wb = ws + WSOFF[p] + (u*16+vv)*nl*3;
      const float* bb = bs + BSOFF[p];
      for(int lk=0; lk<nl; ++lk)
        for(int j=0;j<3;++j)
          acc = fmaf(wb[lk*3+j], bb[((lk*3+j)*A + a)*I + i], acc);
    }
    KB[(size_t)tap*15360 + o] = f2bf(acc);
  }
}

// ---------------- kernel 5: MFMA implicit-GEMM conv, static 6-slot pipeline ----------------
#define RS 104   // LDS row stride (ushorts)
#define MF(a,b,c) __builtin_amdgcn_mfma_f32_16x16x32_bf16(a,b,c,0,0,0)

struct AF { bf16x8 a0,a1,a2,a3,a4; };
struct BF { bf16x8 b0,b1,b2,b3; };

// A-frag load: desc.x = tap*15360
#define LDA_(BUF, dsc, kss) { \
  const u16* ka_ = KB + (dsc).x + hoff + (kss)*2560 + aoff; \
  BUF.a0 = *(const bf16x8*)(ka_);       \
  BUF.a1 = *(const bf16x8*)(ka_+512);   \
  BUF.a2 = *(const bf16x8*)(ka_+1024);  \
  BUF.a3 = *(const bf16x8*)(ka_+1536);  \
  BUF.a4 = *(const bf16x8*)(ka_+2048);  }
// B-frag load: desc.y = (dy*26+dz)*RS
#define LDB_(BUF, dsc, kss) { \
  const u16* bp_ = Bl + (dsc).y + (kss)*32 + boff; \
  BUF.b0 = *(const bf16x8*)(bp_ + rB0); \
  BUF.b1 = *(const bf16x8*)(bp_ + rB1); \
  BUF.b2 = *(const bf16x8*)(bp_ + rB2); \
  BUF.b3 = *(const bf16x8*)(bp_ + rB3); }

#define DOSLOT(Ab,Bb) { \
  __builtin_amdgcn_s_setprio(1); \
  acc[0][0]=MF(Ab.a0,Bb.b0,acc[0][0]); acc[1][0]=MF(Ab.a1,Bb.b0,acc[1][0]); \
  acc[2][0]=MF(Ab.a2,Bb.b0,acc[2][0]); acc[3][0]=MF(Ab.a3,Bb.b0,acc[3][0]); \
  acc[4][0]=MF(Ab.a4,Bb.b0,acc[4][0]); \
  acc[0][1]=MF(Ab.a0,Bb.b1,acc[0][1]); acc[1][1]=MF(Ab.a1,Bb.b1,acc[1][1]); \
  acc[2][1]=MF(Ab.a2,Bb.b1,acc[2][1]); acc[3][1]=MF(Ab.a3,Bb.b1,acc[3][1]); \
  acc[4][1]=MF(Ab.a4,Bb.b1,acc[4][1]); \
  acc[0][2]=MF(Ab.a0,Bb.b2,acc[0][2]); acc[1][2]=MF(Ab.a1,Bb.b2,acc[1][2]); \
  acc[2][2]=MF(Ab.a2,Bb.b2,acc[2][2]); acc[3][2]=MF(Ab.a3,Bb.b2,acc[3][2]); \
  acc[4][2]=MF(Ab.a4,Bb.b2,acc[4][2]); \
  if(NF4){ \
    acc[0][3]=MF(Ab.a0,Bb.b3,acc[0][3]); acc[1][3]=MF(Ab.a1,Bb.b3,acc[1][3]); \
    acc[2][3]=MF(Ab.a2,Bb.b3,acc[2][3]); acc[3][3]=MF(Ab.a3,Bb.b3,acc[3][3]); \
    acc[4][3]=MF(Ab.a4,Bb.b3,acc[4][3]); } \
  __builtin_amdgcn_s_setprio(0); }

// Round-7 lesson: __launch_bounds__(512,2) was interpreted as 2 BLOCKS/CU
// (CUDA semantics) -> 4 waves/EU -> 128-VGPR cap -> spills (250MB scratch).
// Pin the backend attributes directly: waves_per_eu(2,2) -> 256-VGPR budget.
// LDS (140.6KB) caps at 1 block/CU = 2 waves/EU anyway, so no occupancy cost.
__global__ void
__attribute__((amdgpu_flat_work_group_size(512,512), amdgpu_waves_per_eu(2,2)))
conv_mfma(const u16* __restrict__ XB,
    const u16* __restrict__ KB, float* __restrict__ y){
  __shared__ __align__(16) u16 Bl[676*RS];   // 140,608 B
  __shared__ int2 tdesc[37];
  int wg = blockIdx.x;
  int swz = (wg & 7)*30 + (wg >> 3);   // XCD-chunked, bijective (240 = 8*30)
  int xo = swz % 20; int g = (swz/20) % 6; int b = swz/120;
  int tid = threadIdx.x;
  int w = tid>>6, l = tid&63, lrow = l&15, lseg = l>>4;
  int nf0 = (w<7)? w*3 : 21;
  bool NF4 = (w==7);
  int aoff = lrow*32 + lseg*8;
  int boff = lseg*8;
  f32x4 acc[5][4];
  #pragma unroll
  for(int mf=0;mf<5;++mf)
    #pragma unroll
    for(int f=0;f<4;++f) acc[mf][f] = (f32x4){0.f,0.f,0.f,0.f};
  int rB0, rB1, rB2, rB3;
  { int n;
    n=(nf0+0)*16+lrow; rB0=((n/20)*26+(n%20))*RS;
    n=(nf0+1)*16+lrow; rB1=((n/20)*26+(n%20))*RS;
    n=(nf0+2)*16+lrow; rB2=((n/20)*26+(n%20))*RS;
    n=(nf0+3)*16+lrow; rB3=((n/20)*26+(n%20))*RS; }

  int ndx = (g==0)? 2 : 1;
  for(int id=0; id<ndx; ++id){
    int dx = (g==0)? id*6 : g;
    const unsigned char* tl; int nt;
    if(dx==0 || dx==6){ tl = TAP_S; nt = 9; }
    else if(dx==1 || dx==5){ tl = TAP_M; nt = 25; }
    else { tl = TAP_B; nt = 37; }
    __syncthreads();                 // prior pipeline done before desc rewrite
    if(tid < nt){
      int code = tl[tid];
      int dy = code>>4, dz = code&15;
      tdesc[tid] = make_int2((dx*49+dy*7+dz)*15360, (dy*26+dz)*RS);
    }
    for(int half=0; half<2; ++half){
      __syncthreads();
      const u16* src = XB + ((size_t)(b*26 + xo + dx)*2 + half)*XB_SLICE;
      for(int c=tid; c<8112; c+=512){
        ulonglong2 v = ((const ulonglong2*)src)[c];
        int row = c/12, wi = c - row*12;
        *(ulonglong2*)(Bl + row*RS + wi*8) = v;
      }
      __syncthreads();
      int hoff = half*7680;
      AF X, Y, Z; BF P, Q;
      int2 dd0 = tdesc[0];
      LDA_(X, dd0, 0);
      LDA_(Y, dd0, 1);
      LDB_(P, dd0, 0);
      if(half==0){
        // KS = 3 : 2-tap (6-slot) unrolled body, 1-tap epilogue (nt odd)
        int t = 0;
        for(; t+2 < nt; t += 2){
          int2 e0 = tdesc[t], e1 = tdesc[t+1], e2 = tdesc[t+2];
          LDB_(Q, e0, 1);  LDA_(Z, e0, 2);  DOSLOT(X, P);
          LDB_(P, e0, 2);  LDA_(X, e1, 0);  DOSLOT(Y, Q);
          LDB_(Q, e1, 0);  LDA_(Y, e1, 1);  DOSLOT(Z, P);
          LDB_(P, e1, 1);  LDA_(Z, e1, 2);  DOSLOT(X, Q);
          LDB_(Q, e1, 2);  LDA_(X, e2, 0);  DOSLOT(Y, P);
          LDB_(P, e2, 0);  LDA_(Y, e2, 1);  DOSLOT(Z, Q);
        }
        // epilogue tap T = nt-1: X,Y hold (T,0),(T,1); P holds (T,0)
        int2 eT = tdesc[nt-1];
        LDB_(Q, eT, 1);  LDA_(Z, eT, 2);  DOSLOT(X, P);
        LDB_(P, eT, 2);                   DOSLOT(Y, Q);
                                          DOSLOT(Z, P);
      } else {
        // KS = 2 : 3-tap (6-slot) unrolled body, serial tail
        int t = 0;
        for(; t+3 < nt; t += 3){
          int2 e0 = tdesc[t], e1 = tdesc[t+1], e2 = tdesc[t+2], e3 = tdesc[t+3];
          LDB_(Q, e0, 1);  LDA_(Z, e1, 0);  DOSLOT(X, P);
          LDB_(P, e1, 0);  LDA_(X, e1, 1);  DOSLOT(Y, Q);
          LDB_(Q, e1, 1);  LDA_(Y, e2, 0);  DOSLOT(Z, P);
          LDB_(P, e2, 0);  LDA_(Z, e2, 1);  DOSLOT(X, Q);
          LDB_(Q, e2, 1);  LDA_(X, e3, 0);  DOSLOT(Y, P);
          LDB_(P, e3, 0);  LDA_(Y, e3, 1);  DOSLOT(Z, Q);
        }
        // serial tail: taps t..nt-1 (1 or 3 taps), depth-0
        for(; t < nt; ++t){
          int2 eT = tdesc[t];
          LDA_(X, eT, 0);  LDB_(P, eT, 0);  DOSLOT(X, P);
          LDA_(X, eT, 1);  LDB_(P, eT, 1);  DOSLOT(X, P);
        }
      }
    }
  }
  // epilogue: atomic combine across the 6 dx-groups. C/D: col=lane&15 (n), row=(lane>>4)*4+r (co)
  int NFc = NF4 ? 4 : 3;
  #pragma unroll
  for(int f=0; f<4; ++f){
    if(f < NFc){
      int n = (nf0+f)*16 + lrow;
      #pragma unroll
      for(int mf=0; mf<5; ++mf){
        #pragma unroll
        for(int r=0; r<4; ++r){
          int co = mf*16 + lseg*4 + r;
          if(co < 72)
            atomicAdd(&y[((size_t)(b*COUT+co)*20 + xo)*400 + n], acc[mf][f][r]);
        }
      }
    }
  }
}

// ---------------- kernel 6: bn partial sums (grid 24 x 16, atomic combine) ----------------
__global__ __launch_bounds__(256) void bn_partial_kernel(const float* __restrict__ y,
    float* __restrict__ stats){
  int g = blockIdx.x, chunk = blockIdx.y, tid = threadIdx.x;
  int ch0, nc;
  if(g<8){ ch0=g; nc=1; }
  else if(g<16){ ch0=8+(g-8)*3; nc=3; }
  else { ch0=32+(g-16)*5; nc=5; }
  float s=0.f;
  int lo = chunk*1000, hi = lo+1000;
  for(int idx=lo+tid; idx<hi; idx+=256){
    int b = idx/PVOL, p = idx%PVOL;
    const float* yb = y + ((size_t)b*COUT + ch0)*PVOL + p;
    for(int c=0;c<nc;++c){ float v = yb[(size_t)c*PVOL]; s += v*v; }
  }
  __shared__ float red[256];
  red[tid]=s; __syncthreads();
  for(int st=128; st>0; st>>=1){ if(tid<st) red[tid]+=red[tid+st]; __syncthreads(); }
  if(tid==0) atomicAdd(&stats[g], red[0]);
}

// ---------------- kernel 7: apply scale/bias/relu ----------------
__global__ __launch_bounds__(256) void apply_kernel(float* __restrict__ y,
    const float* __restrict__ stats, const float* __restrict__ gamma,
    const float* __restrict__ bias){
  int id = blockIdx.x*256 + threadIdx.x;
  if(id >= 2*COUT*PVOL) return;
  int c = (id/PVOL)%COUT;
  int g = (c<8)? c : ((c<32)? 8+(c-8)/3 : 16+(c-32)/5);
  float scale = gamma[g]*rsqrtf(stats[g]*(1.f/16000.f) + 1e-5f);
  float val = y[id]*scale;
  if(c<8) val = fmaxf(val + bias[c], 0.f);
  y[id] = val;
}

// ---------------- launch ----------------
extern "C" void kernel_launch(void* const* d_in, const int* in_sizes, int n_in,
                              void* d_out, int out_size, void* d_ws, size_t ws_size,
                              hipStream_t stream){
  const float* x = (const float*)d_in[0];
  WPtrs W;
  for(int k=0;k<9;++k) W.p[k] = (const float*)d_in[1+k];
  const float* gamma = (const float*)d_in[10];
  const float* bias  = (const float*)d_in[11];
  char* base = (char*)d_ws;
  float* consts = (float*)base;
  u16* XB = (u16*)(base + OFF_XB_BYTES);
  u16* KB = (u16*)(base + OFF_KB_BYTES);
  float* stats = (float*)(base + OFF_STATS_BYTES);
  float* y = (float*)d_out;

  hipMemsetAsync(XB, 0, XB_BYTES, stream);
  hipMemsetAsync(y, 0, (size_t)2*COUT*PVOL*sizeof(float), stream);
  hipMemsetAsync(stats, 0, 24*sizeof(float), stream);
  gen_all_kernel<<<58,256,0,stream>>>(consts);
  build_xin_kernel<<<(2*MCH*PVOL+255)/256,256,0,stream>>>(x, consts, XB);
  build_K_kernel<<<343,256,0,stream>>>(W, consts, KB);
  conv_mfma<<<240,512,0,stream>>>(XB, KB, y);
  bn_partial_kernel<<<dim3(24,16),256,0,stream>>>(y, stats);
  apply_kernel<<<(2*COUT*PVOL+255)/256,256,0,stream>>>(y, stats, gamma, bias);
}

// Round 11
// 286.322 us; speedup vs baseline: 1.5469x; 1.5445x over previous
//
#include <hip/hip_runtime.h>
#include <hip/hip_bf16.h>
#include <cmath>

typedef unsigned short u16;
typedef __attribute__((ext_vector_type(4))) float f32x4;
typedef __attribute__((ext_vector_type(8))) short bf16x8;

// ---------------- problem constants ----------------
#define PVOL   8000
#define CIN    144
#define COUT   72
#define MCH    8

// ---------------- consts (fp32) float-offset layout ----------------
#define OFF_BASIS 10910
#define CONST_BYTES 1110016    // 277504 floats reserved

// XB: [b2][xi26][half2][yi26][zi26][c96] bf16 (zero-padded borders + ch pad)
#define XB_SLICE  64896        // ushorts per (b,xi,half) = 26*26*96
#define XB_BYTES  13498368
// KB: [tap343][half2][ks3][co80][kk32] bf16
#define KB_ELEMS  5268480
#define KB_BYTES  10536960

#define OFF_XB_BYTES   CONST_BYTES
#define OFF_KB_BYTES   (OFF_XB_BYTES + XB_BYTES)
#define OFF_STATS_BYTES (OFF_KB_BYTES + KB_BYTES)

// 19 basis-CG tasks (pair order (lo,li) = 00,01,02,10,11,12,20,21,22)
static __device__ const int T_LO[19]   = {0,0,0,1, 1,1,1, 1,1,1, 2, 2,2,2, 2,2,2,2,2};
static __device__ const int T_LI[19]   = {0,1,2,0, 1,1,1, 2,2,2, 0, 1,1,1, 2,2,2,2,2};
static __device__ const int T_L [19]   = {0,1,2,1, 0,1,2, 1,2,3, 2, 1,2,3, 0,1,2,3,4};
static __device__ const int PAIR_BOFF[9] = {0,1029,4116,9261,12348,40131,86436,91581,137886};
// build_K LDS staging tables
static __device__ const int NL_P[9]   = {1,1,1,1,3,3,1,3,5};
static __device__ const int WSOFF[9]  = {0,384,768,1152,1536,2688,3840,4224,5376};   // 384*nl cumsum (7296 total)
static __device__ const int BSOFF[9]  = {0,3,12,27,36,117,252,267,402};              // PAIR_BOFF/343 (777 total)

// tap tables: (dy<<4)|dz for the r^2<=12 ball, per |dx-3| class
static __device__ const unsigned char TAP_S[9] = {   // dx in {0,6}
  0x22,0x23,0x24, 0x32,0x33,0x34, 0x42,0x43,0x44};
static __device__ const unsigned char TAP_M[25] = {  // dx in {1,5}
  0x11,0x12,0x13,0x14,0x15, 0x21,0x22,0x23,0x24,0x25,
  0x31,0x32,0x33,0x34,0x35, 0x41,0x42,0x43,0x44,0x45,
  0x51,0x52,0x53,0x54,0x55};
static __device__ const unsigned char TAP_B[37] = {  // dx in {2,3,4}
  0x02,0x03,0x04,
  0x11,0x12,0x13,0x14,0x15,
  0x20,0x21,0x22,0x23,0x24,0x25,0x26,
  0x30,0x31,0x32,0x33,0x34,0x35,0x36,
  0x40,0x41,0x42,0x43,0x44,0x45,0x46,
  0x51,0x52,0x53,0x54,0x55,
  0x62,0x63,0x64};

struct WPtrs { const float* p[9]; };

static __device__ inline u16 f2bf(float v){
  __hip_bfloat16 h = __float2bfloat16(v);
  return __builtin_bit_cast(u16, h);
}

// ---------------- device helpers (fp64) ----------------
__device__ inline double d_fact(int n){ double r=1.0; for(int i=2;i<=n;++i) r*=(double)i; return r; }

__device__ double d_su2cg(int j1,int j2,int j3,int m1,int m2,int m3){
  if(m1+m2!=m3) return 0.0;
  if(j3 < abs(j1-j2) || j3 > j1+j2) return 0.0;
  double pref = sqrt((2.0*j3+1.0)*d_fact(j3+j1-j2)*d_fact(j3-j1+j2)*d_fact(j1+j2-j3)/d_fact(j1+j2+j3+1));
  pref *= sqrt(d_fact(j3+m3)*d_fact(j3-m3)*d_fact(j1-m1)*d_fact(j1+m1)*d_fact(j2-m2)*d_fact(j2+m2));
  double s=0.0;
  for(int k=0;k<=j1+j2+j3;++k){
    int d1=j1+j2-j3-k, d2=j1-m1-k, d3=j2+m2-k, d4=j3-j2+m1+k, d5=j3-j1-m2+k;
    if(d1>=0&&d2>=0&&d3>=0&&d4>=0&&d5>=0)
      s += ((k&1)?-1.0:1.0)/(d_fact(k)*d_fact(d1)*d_fact(d2)*d_fact(d3)*d_fact(d4)*d_fact(d5));
  }
  return pref*s;
}

__device__ inline int d_urow(int l, int r, int* col, double* ure, double* uim){
  const double is2 = 0.7071067811865476;
  if(r==l){ col[0]=l; ure[0]=1.0; uim[0]=0.0; return 1; }
  if(r>l){ int m=r-l; double sg=(m&1)?-1.0:1.0;
    col[0]=l+m; ure[0]=sg*is2; uim[0]=0.0;
    col[1]=l-m; ure[1]=is2;    uim[1]=0.0; return 2; }
  int m=l-r;
  col[0]=l-m; ure[0]=0.0; uim[0]=is2;
  col[1]=l+m; ure[1]=0.0; uim[1]=-(((m&1)?-1.0:1.0))*is2;
  return 2;
}

__device__ void d_sph(double gx,double gy,double gz,double Y[25]){
  const double PI_ = 3.14159265358979323846;
  double r = sqrt(gx*gx+gy*gy+gz*gz);
  const double eps=1e-9;
  double ct = (r>eps)? gz/fmax(r,eps) : 1.0;
  double phi = atan2(gy,gx);
  double st2 = 1.0-ct*ct; if(st2<0.0) st2=0.0;
  double st = sqrt(st2);
  double P[5][5];
  P[0][0]=1.0;
  for(int m=1;m<=4;++m){
    double dfac=1.0; for(int k=1;k<2*m;k+=2) dfac*=(double)k;
    double stm=1.0; for(int k=0;k<m;++k) stm*=st;
    P[m][m] = ((m&1)?-1.0:1.0)*dfac*stm;
  }
  for(int m=0;m<4;++m) P[m+1][m] = ct*(2*m+1)*P[m][m];
  for(int m=0;m<=4;++m)
    for(int l=m+2;l<=4;++l)
      P[l][m] = ((2*l-1)*ct*P[l-1][m] - (l+m-1)*P[l-2][m])/(double)(l-m);
  int idx=0;
  for(int l=0;l<=4;++l){
    double arr[9];
    for(int k=0;k<2*l+1;++k) arr[k]=0.0;
    for(int m=0;m<=l;++m){
      double N = sqrt((2.0*l+1.0)/(4.0*PI_)*d_fact(l-m)/d_fact(l+m));
      if(m==0) arr[l] = N*P[l][0];
      else{
        arr[l+m]=sqrt(2.0)*N*P[l][m]*cos(m*phi);
        arr[l-m]=sqrt(2.0)*N*P[l][m]*sin(m*phi);
      }
    }
    if(l>0 && !(r>eps)) for(int k=0;k<2*l+1;++k) arr[k]=0.0;
    for(int k=0;k<2*l+1;++k) Y[idx++]=arr[k];
  }
}

// ---------------- kernel 1: fused CG + Y + RAD + basis (+ TPC) ----------------
__global__ __launch_bounds__(256) void gen_all_kernel(float* __restrict__ consts){
  __shared__ double Cc[225];
  __shared__ float  Tt[225];
  __shared__ float  Ylds[9*343];
  __shared__ float  Rlds[343];
  __shared__ double mre[256], mim[256];
  __shared__ double red[256];
  int tid = threadIdx.x;

  if(blockIdx.x == 57){
    for(int l=0;l<3;++l){
      int n1=3, n2=3, n3=2*l+1, cnt=n1*n2*n3;
      int outOff = (l==0)?0:((l==1)?9:36);
      __syncthreads();
      for(int e=tid;e<cnt;e+=256){
        int m=e/(n2*n3), n=(e/n3)%n2, c=e%n3;
        Cc[e]=d_su2cg(1,1,l, m-1, n-1, c-l);
      }
      __syncthreads();
      double tre=0.0, tim=0.0;
      int e=tid;
      if(e<cnt){
        int a=e/(n1*n2), i=(e/n2)%n1, jj=e%n2;
        int c3[2]; double r3[2], q3[2]; int nc3=d_urow(l,a,c3,r3,q3);
        int c1[2]; double r1[2], q1[2]; int nc1=d_urow(1,i,c1,r1,q1);
        int c2[2]; double r2[2], q2[2]; int nc2=d_urow(1,jj,c2,r2,q2);
        for(int ic=0; ic<nc3; ++ic)
          for(int im=0; im<nc1; ++im)
            for(int in_=0; in_<nc2; ++in_){
              double cc = Cc[(c1[im]*n2 + c2[in_])*n3 + c3[ic]];
              if(cc==0.0) continue;
              double ar=r3[ic], ai=q3[ic];
              double br=r1[im], bi=-q1[im];
              double cr=r2[in_], cim=-q2[in_];
              double abr = ar*br - ai*bi, abi = ar*bi + ai*br;
              double zr = abr*cr - abi*cim, zi = abr*cim + abi*cr;
              tre += zr*cc; tim += zi*cc;
            }
      }
      mre[tid]=fabs(tre); mim[tid]=fabs(tim);
      __syncthreads();
      for(int s=128;s>0;s>>=1){ if(tid<s){ mre[tid]=fmax(mre[tid],mre[tid+s]); mim[tid]=fmax(mim[tid],mim[tid+s]); } __syncthreads(); }
      bool useim = mim[0] > mre[0];
      if(e<cnt) consts[outOff + e] = (float)(useim? tim : tre);
      __syncthreads();
    }
    return;
  }

  int task = blockIdx.x/3, jrad = blockIdx.x%3;
  int lo=T_LO[task], li=T_LI[task], l=T_L[task];
  int j1=li, j2=l, j3=lo;
  int n1=2*j1+1, n2=2*j2+1, n3=2*j3+1, cnt=n1*n2*n3;
  for(int e=tid;e<cnt;e+=256){
    int m=e/(n2*n3), n=(e/n3)%n2, c=e%n3;
    Cc[e]=d_su2cg(j1,j2,j3, m-j1, n-j2, c-j3);
  }
  __syncthreads();
  double tre=0.0, tim=0.0;
  int e=tid;
  if(e<cnt){
    int a=e/(n1*n2), i=(e/n2)%n1, jj=e%n2;
    int c3[2]; double r3[2], q3[2]; int nc3=d_urow(j3,a,c3,r3,q3);
    int c1[2]; double r1[2], q1[2]; int nc1=d_urow(j1,i,c1,r1,q1);
    int c2[2]; double r2[2], q2[2]; int nc2=d_urow(j2,jj,c2,r2,q2);
    for(int ic=0; ic<nc3; ++ic)
      for(int im=0; im<nc1; ++im)
        for(int in_=0; in_<nc2; ++in_){
          double cc = Cc[(c1[im]*n2 + c2[in_])*n3 + c3[ic]];
          if(cc==0.0) continue;
          double ar=r3[ic], ai=q3[ic];
          double br=r1[im], bi=-q1[im];
          double cr=r2[in_], cim=-q2[in_];
          double abr = ar*br - ai*bi, abi = ar*bi + ai*br;
          double zr = abr*cr - abi*cim, zi = abr*cim + abi*cr;
          tre += zr*cc; tim += zi*cc;
        }
  }
  mre[tid]=fabs(tre); mim[tid]=fabs(tim);
  __syncthreads();
  for(int s=128;s>0;s>>=1){ if(tid<s){ mre[tid]=fmax(mre[tid],mre[tid+s]); mim[tid]=fmax(mim[tid],mim[tid+s]); } __syncthreads(); }
  bool useim = mim[0] > mre[0];
  if(e<cnt) Tt[e] = (float)(useim? tim : tre);
  for(int t=tid; t<343; t+=256){
    int ix=t/49, iy=(t/7)%7, iz=t%7;
    double gx=ix-3, gy=iy-3, gz=iz-3;
    double Y25[25]; d_sph(gx,gy,gz,Y25);
    for(int m=0;m<n2;++m) Ylds[m*343+t] = (float)Y25[l*l+m];
    double r = sqrt(gx*gx+gy*gy+gz*gz);
    double d = r - 1.5*jrad;
    Rlds[t] = (r<=3.5)? (float)exp(-0.5*d*d) : 0.0f;
  }
  __syncthreads();
  int A=2*lo+1, I=2*li+1;
  int l_idx = l - abs(lo-li);
  float* out = consts + OFF_BASIS + PAIR_BOFF[lo*3+li] + (size_t)((l_idx*3 + jrad)*A*I)*343;
  int N = A*I*343;
  double ssq = 0.0;
  for(int ee=tid; ee<N; ee+=256){
    int ai = ee/343, t = ee%343;
    double ang = 0.0;
    for(int m=0;m<n2;++m) ang += (double)Tt[ai*n2+m] * (double)Ylds[m*343+t];
    double val = ang * (double)Rlds[t];
    out[ee] = (float)val;
    ssq += val*val;
  }
  red[tid]=ssq; __syncthreads();
  for(int s=128;s>0;s>>=1){ if(tid<s) red[tid]+=red[tid+s]; __syncthreads(); }
  double nrm = sqrt(red[0]);
  float scale = (nrm>1e-12)? (float)(1.0/nrm) : 1.0f;
  for(int ee=tid; ee<N; ee+=256) out[ee] *= scale;
}

// ---------------- kernel 3: build padded bf16 xin (fragment-native layout) ----------------
__global__ __launch_bounds__(256) void build_xin_kernel(const float* __restrict__ x,
    const float* __restrict__ consts, u16* __restrict__ XB){
  int id = blockIdx.x*256 + threadIdx.x;
  if(id >= 2*MCH*PVOL) return;
  int p = id % PVOL; int u = (id/PVOL)%MCH; int b = id/(MCH*PVOL);
  int xi=p/400, rr=p%400, yi=rr/20, zi=rr%20;
  const float* xb = x + (size_t)b*COUT*PVOL + p;
  float s  = xb[(size_t)u*PVOL];
  float vv[3], qq[5];
  for(int i=0;i<3;++i) vv[i] = xb[(size_t)(8+u*3+i)*PVOL];
  for(int i=0;i<5;++i) qq[i] = xb[(size_t)(32+u*5+i)*PVOL];
  const float* T0 = consts + 0;
  const float* T1 = consts + 9;
  const float* T2 = consts + 36;
  float i0=0.f, i1[3]={0,0,0}, i2[5]={0,0,0,0,0};
  for(int i=0;i<3;++i) for(int jj=0;jj<3;++jj){
    float vij = vv[i]*vv[jj];
    i0 += T0[i*3+jj]*vij;
    for(int a=0;a<3;++a) i1[a] += T1[(a*3+i)*3+jj]*vij;
    for(int a=0;a<5;++a) i2[a] += T2[(a*3+i)*3+jj]*vij;
  }
  size_t base_b = ((size_t)b*26 + (xi+3))*2;
  size_t pos = ((size_t)(yi+3))*26 + (zi+3);
  auto wr = [&](int ci, float v){
    int h = ci>=80 ? 1 : 0; int cl = ci - 80*h;
    XB[(base_b + h)*XB_SLICE + pos*96 + cl] = f2bf(v);
  };
  wr(u, s);
  wr(8+u, i0);
  for(int i=0;i<3;++i) wr(16+u*3+i, vv[i]);
  for(int a=0;a<3;++a) wr(40+u*3+a, i1[a]);
  for(int i=0;i<5;++i) wr(64+u*5+i, qq[i]);
  for(int a=0;a<5;++a) wr(104+u*5+a, i2[a]);
}

// ---------------- kernel 4: build K (one block per tap, LDS-staged w+basis) ----------------
__global__ __launch_bounds__(256) void build_K_kernel(WPtrs W,
    const float* __restrict__ consts, u16* __restrict__ KB){
  int tap = blockIdx.x, tid = threadIdx.x;
  __shared__ float ws[7296];
  __shared__ float bs[777];
  for(int p=0;p<9;++p){
    int n = 384*NL_P[p];
    const float* wp = W.p[p];
    for(int e=tid; e<n; e+=256) ws[WSOFF[p]+e] = wp[e];
  }
  for(int f=tid; f<777; f+=256) bs[f] = consts[OFF_BASIS + f*343 + tap];
  __syncthreads();
  for(int o=tid; o<15360; o+=256){
    int kk = o&31;
    int co = (o>>5)%80;
    int ks = (o/2560)%3;
    int half = o/7680;
    int ci_l = ks*32 + kk;
    float acc = 0.f;
    bool valid = (co<72) && (half==0 ? (ci_l<80) : (ci_l<64));
    if(valid){
      int ci = half*80 + ci_l;
      int lo,u,a;
      if(co<8){ lo=0; u=co; a=0; }
      else if(co<32){ lo=1; u=(co-8)/3; a=(co-8)%3; }
      else { lo=2; u=(co-32)/5; a=(co-32)%5; }
      int li,vv,i;
      if(ci<16){ li=0; vv=ci; i=0; }
      else if(ci<64){ li=1; vv=(ci-16)/3; i=(ci-16)%3; }
      else { li=2; vv=(ci-64)/5; i=(ci-64)%5; }
      int p = lo*3+li;
      int nl = NL_P[p];
      int A = 2*lo+1, I = 2*li+1;
      const float* wb = ws + WSOFF[p] + (u*16+vv)*nl*3;
      const float* bb = bs + BSOFF[p];
      for(int lk=0; lk<nl; ++lk)
        for(int j=0;j<3;++j)
          acc = fmaf(wb[lk*3+j], bb[((lk*3+j)*A + a)*I + i], acc);
    }
    KB[(size_t)tap*15360 + o] = f2bf(acc);
  }
}

// ---------------- kernel 5: MFMA implicit-GEMM conv, 32-ch LDS slices ----------------
// LDS cut 140.6KB -> 48.7KB so 2 blocks/CU co-reside (4 waves/SIMD): wave-level
// TLP hides the serial load->MFMA latency (round-4 structure was correct but
// 1 block/CU = no overlap). Intrinsic MFMA only (compiler AGPR-allocates acc).
#define RS2 36   // 32 ch + 4 pad (u16); bank stride 18 mod 32 -> <=2-way (free)
#define MF(a,b,c) __builtin_amdgcn_mfma_f32_16x16x32_bf16(a,b,c,0,0,0)

__global__ __launch_bounds__(512) void conv_mfma(const u16* __restrict__ XB,
    const u16* __restrict__ KB, float* __restrict__ y){
  __shared__ __align__(16) u16 Bl[676*RS2];   // 48,672 B
  __shared__ int2 tdesc[37];
  int wg = blockIdx.x;
  int swz = (wg & 7)*30 + (wg >> 3);   // XCD-chunked, bijective (240 = 8*30)
  int xo = swz % 20; int g = (swz/20) % 6; int b = swz/120;
  int tid = threadIdx.x;
  int w = tid>>6, l = tid&63, lrow = l&15, lseg = l>>4;
  int nf0 = (w<7)? w*3 : 21;
  int NF  = (w<7)? 3 : 4;
  int aoff = lrow*32 + lseg*8;
  int boff = lseg*8;
  f32x4 acc[5][4];
  #pragma unroll
  for(int mf=0;mf<5;++mf)
    #pragma unroll
    for(int f=0;f<4;++f) acc[mf][f] = (f32x4){0.f,0.f,0.f,0.f};
  int row0[4];
  #pragma unroll
  for(int f=0;f<4;++f){ int n=(nf0+f)*16+lrow; row0[f]=((n/20)*26+(n%20))*RS2; }

  int ndx = (g==0)? 2 : 1;
  for(int id=0; id<ndx; ++id){
    int dx = (g==0)? id*6 : g;
    const unsigned char* tl; int nt;
    if(dx==0 || dx==6){ tl = TAP_S; nt = 9; }
    else if(dx==1 || dx==5){ tl = TAP_M; nt = 25; }
    else { tl = TAP_B; nt = 37; }
    __syncthreads();                 // previous dx fully consumed before rewrite
    if(tid < nt){
      int code = tl[tid];
      int dy = code>>4, dz = code&15;
      tdesc[tid] = make_int2((dx*49+dy*7+dz)*15360, (dy*26+dz)*RS2);
    }
    // 5 passes: (half0, ks0..2), (half1, ks0..1). half1 ks2 is zero padding.
    for(int pass=0; pass<5; ++pass){
      int half = (pass<3)? 0 : 1;
      int ks   = (pass<3)? pass : pass-3;
      __syncthreads();
      const u16* src = XB + ((size_t)(b*26 + xo + dx)*2 + half)*XB_SLICE + ks*32;
      for(int c=tid; c<2704; c+=512){       // 676 pos x 4 x 16B
        int pos = c>>2, wi = c&3;
        ulonglong2 v = *(const ulonglong2*)(src + pos*96 + wi*8);
        *(ulonglong2*)(Bl + pos*RS2 + wi*8) = v;
      }
      __syncthreads();
      int hk = half*7680 + ks*2560;
      for(int t=0; t<nt; ++t){
        int2 e = tdesc[t];
        const u16* ka = KB + e.x + hk + aoff;
        bf16x8 af[5];
        #pragma unroll
        for(int mf=0;mf<5;++mf) af[mf] = *(const bf16x8*)(ka + mf*512);
        #pragma unroll
        for(int f=0; f<4; ++f){
          if(f < NF){
            bf16x8 bv = *(const bf16x8*)(Bl + row0[f] + e.y + boff);
            #pragma unroll
            for(int mf=0;mf<5;++mf)
              acc[mf][f] = MF(af[mf], bv, acc[mf][f]);
          }
        }
      }
    }
  }
  // epilogue: atomic combine across the 6 dx-groups. C/D: col=lane&15 (n), row=(lane>>4)*4+r (co)
  #pragma unroll
  for(int f=0; f<4; ++f){
    if(f < NF){
      int n = (nf0+f)*16 + lrow;
      #pragma unroll
      for(int mf=0; mf<5; ++mf){
        #pragma unroll
        for(int r=0; r<4; ++r){
          int co = mf*16 + lseg*4 + r;
          if(co < 72)
            atomicAdd(&y[((size_t)(b*COUT+co)*20 + xo)*400 + n], acc[mf][f][r]);
        }
      }
    }
  }
}

// ---------------- kernel 6: bn partial sums (grid 24 x 16, atomic combine) ----------------
__global__ __launch_bounds__(256) void bn_partial_kernel(const float* __restrict__ y,
    float* __restrict__ stats){
  int g = blockIdx.x, chunk = blockIdx.y, tid = threadIdx.x;
  int ch0, nc;
  if(g<8){ ch0=g; nc=1; }
  else if(g<16){ ch0=8+(g-8)*3; nc=3; }
  else { ch0=32+(g-16)*5; nc=5; }
  float s=0.f;
  int lo = chunk*1000, hi = lo+1000;
  for(int idx=lo+tid; idx<hi; idx+=256){
    int b = idx/PVOL, p = idx%PVOL;
    const float* yb = y + ((size_t)b*COUT + ch0)*PVOL + p;
    for(int c=0;c<nc;++c){ float v = yb[(size_t)c*PVOL]; s += v*v; }
  }
  __shared__ float red[256];
  red[tid]=s; __syncthreads();
  for(int st=128; st>0; st>>=1){ if(tid<st) red[tid]+=red[tid+st]; __syncthreads(); }
  if(tid==0) atomicAdd(&stats[g], red[0]);
}

// ---------------- kernel 7: apply scale/bias/relu ----------------
__global__ __launch_bounds__(256) void apply_kernel(float* __restrict__ y,
    const float* __restrict__ stats, const float* __restrict__ gamma,
    const float* __restrict__ bias){
  int id = blockIdx.x*256 + threadIdx.x;
  if(id >= 2*COUT*PVOL) return;
  int c = (id/PVOL)%COUT;
  int g = (c<8)? c : ((c<32)? 8+(c-8)/3 : 16+(c-32)/5);
  float scale = gamma[g]*rsqrtf(stats[g]*(1.f/16000.f) + 1e-5f);
  float val = y[id]*scale;
  if(c<8) val = fmaxf(val + bias[c], 0.f);
  y[id] = val;
}

// ---------------- launch ----------------
extern "C" void kernel_launch(void* const* d_in, const int* in_sizes, int n_in,
                              void* d_out, int out_size, void* d_ws, size_t ws_size,
                              hipStream_t stream){
  const float* x = (const float*)d_in[0];
  WPtrs W;
  for(int k=0;k<9;++k) W.p[k] = (const float*)d_in[1+k];
  const float* gamma = (const float*)d_in[10];
  const float* bias  = (const float*)d_in[11];
  char* base = (char*)d_ws;
  float* consts = (float*)base;
  u16* XB = (u16*)(base + OFF_XB_BYTES);
  u16* KB = (u16*)(base + OFF_KB_BYTES);
  float* stats = (float*)(base + OFF_STATS_BYTES);
  float* y = (float*)d_out;

  hipMemsetAsync(XB, 0, XB_BYTES, stream);
  hipMemsetAsync(y, 0, (size_t)2*COUT*PVOL*sizeof(float), stream);
  hipMemsetAsync(stats, 0, 24*sizeof(float), stream);
  gen_all_kernel<<<58,256,0,stream>>>(consts);
  build_xin_kernel<<<(2*MCH*PVOL+255)/256,256,0,stream>>>(x, consts, XB);
  build_K_kernel<<<343,256,0,stream>>>(W, consts, KB);
  conv_mfma<<<240,512,0,stream>>>(XB, KB, y);
  bn_partial_kernel<<<dim3(24,16),256,0,stream>>>(y, stats);
  apply_kernel<<<(2*COUT*PVOL+255)/256,256,0,stream>>>(y, stats, gamma, bias);
}